// Round 1
// baseline (2917.290 us; speedup 1.0000x reference)
//
#include <hip/hip_runtime.h>
#include <hip/hip_bf16.h>
#include <stdint.h>

#define DIM 256
#define TOPK 8
#define NSTRIPS 32
#define STRIP_TOP 16
#define QT 64
#define NT 64
#define CAND (NSTRIPS * STRIP_TOP)   // 512
#define RESCORE 64
#define LDSM_STRIDE 264              // 256 + 8 shorts pad -> breaks bank conflicts

typedef __attribute__((ext_vector_type(8))) short short8;
typedef __attribute__((ext_vector_type(4))) float floatx4;

__device__ __forceinline__ unsigned short f2bf(float f) {
    union { float f; uint32_t u; } v; v.f = f;
    uint32_t u = v.u;
    uint32_t r = u + 0x7fffu + ((u >> 16) & 1u);   // round-to-nearest-even
    return (unsigned short)(r >> 16);
}

// ---------------- Kernel 1: norms + normalized bf16 query ----------------
__global__ void prep_kernel(const float* __restrict__ query,
                            const float* __restrict__ mem,
                            float* __restrict__ rnorm_mem,
                            unsigned short* __restrict__ q_bf16,
                            int B, int N)
{
    int wave = threadIdx.x >> 6;
    int lane = threadIdx.x & 63;
    int row  = blockIdx.x * 4 + wave;
    int total = N + B;
    if (row >= total) return;
    const float* src = (row < N) ? (mem + (size_t)row * DIM)
                                 : (query + (size_t)(row - N) * DIM);
    float4 v = ((const float4*)src)[lane];
    float ss = v.x * v.x + v.y * v.y + v.z * v.z + v.w * v.w;
#pragma unroll
    for (int m = 32; m >= 1; m >>= 1) ss += __shfl_xor(ss, m, 64);
    float rinv = 1.0f / fmaxf(sqrtf(ss), 1e-12f);
    if (row < N) {
        if (lane == 0) rnorm_mem[row] = rinv;
    } else {
        int qr = row - N;
        ushort4 o;
        o.x = f2bf(v.x * rinv); o.y = f2bf(v.y * rinv);
        o.z = f2bf(v.z * rinv); o.w = f2bf(v.w * rinv);
        ((ushort4*)(q_bf16 + (size_t)qr * DIM))[lane] = o;
    }
}

// ---------------- Kernel 2: fused bf16-MFMA scoring + per-strip top-16 ----------------
__global__ __launch_bounds__(256, 2) void score_select_kernel(
    const float* __restrict__ mem,
    const float* __restrict__ rnorm_mem,
    const unsigned short* __restrict__ q_bf16,
    int* __restrict__ cand_idx,
    float* __restrict__ cand_score,
    int B, int N)
{
    __shared__ unsigned short lds_m[NT * LDSM_STRIDE];  // 33792 B
    __shared__ float lds_s[QT * 65];                    // 16640 B (pad 65 vs banks)
    __shared__ float top_s[QT * STRIP_TOP];             // 4096 B, ascending per query
    __shared__ int   top_i[QT * STRIP_TOP];             // 4096 B

    const int t    = threadIdx.x;
    const int wave = t >> 6;
    const int lane = t & 63;
    const int quad = lane >> 4;
    const int l16  = lane & 15;

    const int qbase = blockIdx.x * QT;
    const int strip = blockIdx.y;
    const int SS    = (N + NSTRIPS - 1) / NSTRIPS;
    const int n0    = strip * SS;
    const int nend  = (n0 + SS < N) ? (n0 + SS) : N;
    const int ntiles = (nend - n0 + NT - 1) / NT;

    for (int i = t; i < QT * STRIP_TOP; i += 256) { top_s[i] = -1e30f; top_i[i] = 0; }

    // A fragments: this wave's 16 query rows, full K=256, resident in registers.
    short8 afrag[8];
    {
        int qrow = qbase + wave * 16 + l16;
        if (qrow < B) {
            const unsigned short* qp = q_bf16 + (size_t)qrow * DIM + quad * 8;
#pragma unroll
            for (int ks = 0; ks < 8; ks++)
                afrag[ks] = *(const short8*)(qp + ks * 32);
        } else {
#pragma unroll
            for (int ks = 0; ks < 8; ks++)
#pragma unroll
                for (int j = 0; j < 8; j++) afrag[ks][j] = 0;
        }
    }

    auto stage = [&](int tileIdx) {
        int base = n0 + tileIdx * NT;
#pragma unroll 4
        for (int i = 0; i < 16; i++) {
            int r = i * 4 + wave;
            int n = base + r;
            ushort4 o;
            if (n < nend) {
                float rinv = rnorm_mem[n];
                float4 v = ((const float4*)(mem + (size_t)n * DIM))[lane];
                o.x = f2bf(v.x * rinv); o.y = f2bf(v.y * rinv);
                o.z = f2bf(v.z * rinv); o.w = f2bf(v.w * rinv);
            } else {
                o.x = 0; o.y = 0; o.z = 0; o.w = 0;
            }
            *(ushort4*)(lds_m + r * LDSM_STRIDE + lane * 4) = o;
        }
    };

    stage(0);
    __syncthreads();

    const floatx4 zero4 = {0.f, 0.f, 0.f, 0.f};
    for (int tile = 0; tile < ntiles; tile++) {
        floatx4 acc[4];
#pragma unroll
        for (int nt = 0; nt < 4; nt++) acc[nt] = zero4;
#pragma unroll
        for (int ks = 0; ks < 8; ks++) {
#pragma unroll
            for (int nt = 0; nt < 4; nt++) {
                short8 b = *(const short8*)(lds_m + (nt * 16 + l16) * LDSM_STRIDE
                                            + ks * 32 + quad * 8);
                acc[nt] = __builtin_amdgcn_mfma_f32_16x16x32_bf16(afrag[ks], b, acc[nt], 0, 0, 0);
            }
        }
        // C layout: col = lane&15 (n), row = quad*4 + reg (q)
#pragma unroll
        for (int nt = 0; nt < 4; nt++)
#pragma unroll
            for (int r = 0; r < 4; r++)
                lds_s[(wave * 16 + quad * 4 + r) * 65 + nt * 16 + l16] = acc[nt][r];
        __syncthreads();

        if (tile + 1 < ntiles) stage(tile + 1);   // overlap staging with selection

        if (t < QT) {   // wave 0: one query per lane, scan 64 scores, keep top-16
            int tbase = n0 + tile * NT;
            int valid = nend - tbase; if (valid > NT) valid = NT;
            float* ts = top_s + t * STRIP_TOP;
            int*   ti = top_i + t * STRIP_TOP;
            for (int c = 0; c < valid; c++) {
                float s = lds_s[t * 65 + c];
                if (s > ts[0]) {
                    int p = 1;
                    while (p < STRIP_TOP && s > ts[p]) {
                        ts[p - 1] = ts[p]; ti[p - 1] = ti[p]; p++;
                    }
                    ts[p - 1] = s; ti[p - 1] = tbase + c;
                }
            }
        }
        __syncthreads();
    }

    for (int i = t; i < QT * STRIP_TOP; i += 256) {
        int q = i / STRIP_TOP;
        int gq = qbase + q;
        if (gq < B) {
            size_t off = ((size_t)gq * NSTRIPS + strip) * STRIP_TOP + (i % STRIP_TOP);
            cand_score[off] = top_s[i];
            cand_idx[off]   = top_i[i];
        }
    }
}

// ---------------- Kernel 3: merge candidates, fp64 exact rescore, top-8, gather ----------------
__global__ __launch_bounds__(256) void rescore_kernel(
    const float* __restrict__ query,
    const float* __restrict__ mem,
    const int* __restrict__ cand_idx,
    const float* __restrict__ cand_score,
    float* __restrict__ out,
    int B, int N)
{
    __shared__ float  cs[CAND];
    __shared__ int    ci[CAND];
    __shared__ float  lds_q[DIM];
    __shared__ double red[4];
    __shared__ double qss_sh;
    __shared__ double rs[RESCORE];
    __shared__ double best_s[TOPK];
    __shared__ int    best_i[TOPK];

    const int t    = threadIdx.x;
    const int q    = blockIdx.x;
    const int lane = t & 63;
    const int wave = t >> 6;

    for (int i = t; i < CAND; i += 256) {
        size_t off = (size_t)q * CAND + i;
        cs[i] = cand_score[off];
        ci[i] = cand_idx[off];
    }

    // q row to LDS + sum of squares (fp64)
    float qv = query[(size_t)q * DIM + t];
    lds_q[t] = qv;
    double p = (double)qv * (double)qv;
#pragma unroll
    for (int m = 32; m >= 1; m >>= 1) p += __shfl_xor(p, m, 64);
    if (lane == 0) red[wave] = p;
    __syncthreads();
    if (t == 0) qss_sh = red[0] + red[1] + red[2] + red[3];

    // bitonic sort 512 by (score desc, idx asc)
    for (int k = 2; k <= CAND; k <<= 1) {
        for (int j = k >> 1; j > 0; j >>= 1) {
            __syncthreads();
            int i  = 2 * t - (t & (j - 1));
            int ip = i + j;
            bool up = ((i & k) == 0);
            float s0 = cs[i], s1 = cs[ip];
            int   i0 = ci[i], i1 = ci[ip];
            bool aFirst = (s0 > s1) || (s0 == s1 && i0 < i1);
            bool doSwap = up ? (!aFirst) : aFirst;
            if (doSwap) { cs[i] = s1; ci[i] = i1; cs[ip] = s0; ci[ip] = i0; }
        }
    }
    __syncthreads();

    // fp64 exact cosine for top-64 candidates; one candidate per wave round-robin
    double qss = qss_sh;
    for (int c = wave; c < RESCORE; c += 4) {
        int idx = ci[c];
        float4 mv = ((const float4*)(mem + (size_t)idx * DIM))[lane];
        float4 qv4 = ((const float4*)lds_q)[lane];
        double dqm = (double)mv.x * (double)qv4.x + (double)mv.y * (double)qv4.y
                   + (double)mv.z * (double)qv4.z + (double)mv.w * (double)qv4.w;
        double dmm = (double)mv.x * (double)mv.x + (double)mv.y * (double)mv.y
                   + (double)mv.z * (double)mv.z + (double)mv.w * (double)mv.w;
#pragma unroll
        for (int m = 32; m >= 1; m >>= 1) {
            dqm += __shfl_xor(dqm, m, 64);
            dmm += __shfl_xor(dmm, m, 64);
        }
        if (lane == 0)
            rs[c] = dqm / (fmax(sqrt(qss), 1e-12) * fmax(sqrt(dmm), 1e-12));
    }
    __syncthreads();

    if (t == 0) {   // serial exact top-8 with jax tie-break (score desc, idx asc)
        double bs[TOPK]; int bi[TOPK];
        for (int i = 0; i < TOPK; i++) { bs[i] = -1e300; bi[i] = 0x7fffffff; }
        for (int c = 0; c < RESCORE; c++) {
            double s = rs[c]; int id = ci[c];
            bool better = (s > bs[TOPK - 1]) || (s == bs[TOPK - 1] && id < bi[TOPK - 1]);
            if (better) {
                int pos = TOPK - 1;
                while (pos > 0) {
                    bool b2 = (s > bs[pos - 1]) || (s == bs[pos - 1] && id < bi[pos - 1]);
                    if (!b2) break;
                    bs[pos] = bs[pos - 1]; bi[pos] = bi[pos - 1]; pos--;
                }
                bs[pos] = s; bi[pos] = id;
            }
        }
        for (int i = 0; i < TOPK; i++) { best_s[i] = bs[i]; best_i[i] = bi[i]; }
    }
    __syncthreads();

    size_t score_base = (size_t)B * TOPK * DIM;
    if (t < TOPK) out[score_base + (size_t)q * TOPK + t] = (float)best_s[t];

#pragma unroll
    for (int rep = 0; rep < 2; rep++) {
        int j  = t >> 5;
        int d4 = (t & 31) + rep * 32;
        int idx = best_i[j];
        float4 v = ((const float4*)(mem + (size_t)idx * DIM))[d4];
        ((float4*)(out + ((size_t)q * TOPK + j) * DIM))[d4] = v;
    }
}

extern "C" void kernel_launch(void* const* d_in, const int* in_sizes, int n_in,
                              void* d_out, int out_size, void* d_ws, size_t ws_size,
                              hipStream_t stream)
{
    const float* query = (const float*)d_in[0];
    const float* mem   = (const float*)d_in[1];
    int B = in_sizes[0] / DIM;
    int N = in_sizes[1] / DIM;

    char* ws = (char*)d_ws;
    float* rnorm_mem = (float*)ws;                 ws += (((size_t)N * 4) + 255) & ~(size_t)255;
    unsigned short* q_bf16 = (unsigned short*)ws;  ws += (((size_t)B * DIM * 2) + 255) & ~(size_t)255;
    int* cand_idx = (int*)ws;                      ws += (((size_t)B * CAND * 4) + 255) & ~(size_t)255;
    float* cand_score = (float*)ws;                ws += (((size_t)B * CAND * 4) + 255) & ~(size_t)255;

    int prep_blocks = (N + B + 3) / 4;
    prep_kernel<<<prep_blocks, 256, 0, stream>>>(query, mem, rnorm_mem, q_bf16, B, N);

    dim3 g2((B + QT - 1) / QT, NSTRIPS);
    score_select_kernel<<<g2, 256, 0, stream>>>(mem, rnorm_mem, q_bf16,
                                                cand_idx, cand_score, B, N);

    rescore_kernel<<<B, 256, 0, stream>>>(query, mem, cand_idx, cand_score,
                                          (float*)d_out, B, N);
}

// Round 2
// 711.894 us; speedup vs baseline: 4.0979x; 4.0979x over previous
//
#include <hip/hip_runtime.h>
#include <hip/hip_bf16.h>
#include <stdint.h>

#define DIM 256
#define TOPK 8
#define NSTRIPS 32
#define STRIP_TOP 16                 // merged candidates per (query,strip)
#define SUB_TOP 8                    // per-thread (query,quarter) top-k
#define QT 64
#define NT 64
#define CAND (NSTRIPS * STRIP_TOP)   // 512
#define RESCORE 64

typedef __attribute__((ext_vector_type(8))) short short8;
typedef __attribute__((ext_vector_type(4))) float floatx4;
typedef __attribute__((address_space(3))) unsigned int lds_u32;
typedef __attribute__((address_space(1))) const unsigned int gbl_u32;

__device__ __forceinline__ unsigned short f2bf(float f) {
    union { float f; uint32_t u; } v; v.f = f;
    uint32_t u = v.u;
    uint32_t r = u + 0x7fffu + ((u >> 16) & 1u);   // RNE
    return (unsigned short)(r >> 16);
}

// ---------------- Kernel 1: norms + normalized bf16 copies ----------------
__global__ void prep_kernel(const float* __restrict__ query,
                            const float* __restrict__ mem,
                            float* __restrict__ rnorm_mem,
                            unsigned short* __restrict__ q_bf16,
                            unsigned short* __restrict__ mem_bf16,  // may be null
                            int B, int N)
{
    int wave = threadIdx.x >> 6;
    int lane = threadIdx.x & 63;
    int row  = blockIdx.x * 4 + wave;
    int total = N + B;
    if (row >= total) return;
    const float* src = (row < N) ? (mem + (size_t)row * DIM)
                                 : (query + (size_t)(row - N) * DIM);
    float4 v = ((const float4*)src)[lane];
    float ss = v.x * v.x + v.y * v.y + v.z * v.z + v.w * v.w;
#pragma unroll
    for (int m = 32; m >= 1; m >>= 1) ss += __shfl_xor(ss, m, 64);
    float rinv = 1.0f / fmaxf(sqrtf(ss), 1e-12f);
    ushort4 o;
    o.x = f2bf(v.x * rinv); o.y = f2bf(v.y * rinv);
    o.z = f2bf(v.z * rinv); o.w = f2bf(v.w * rinv);
    if (row < N) {
        if (lane == 0) rnorm_mem[row] = rinv;
        if (mem_bf16) ((ushort4*)(mem_bf16 + (size_t)row * DIM))[lane] = o;
    } else {
        ((ushort4*)(q_bf16 + (size_t)(row - N) * DIM))[lane] = o;
    }
}

// ---------------- Kernel 2: fused bf16-MFMA scoring + parallel top-k ----------------
template<bool PRE>
__global__ __launch_bounds__(256, 3) void score_select_kernel(
    const float* __restrict__ mem,
    const float* __restrict__ rnorm_mem,
    const unsigned short* __restrict__ mem_bf16,
    const unsigned short* __restrict__ q_bf16,
    int* __restrict__ cand_idx,
    float* __restrict__ cand_score,
    int B, int N)
{
    __shared__ unsigned short lds_m[NT * DIM];   // 32768 B, XOR-swizzled rows
    __shared__ float lds_s[NT * 68];             // 17408 B, [n][q] stride 68

    const int t    = threadIdx.x;
    const int wave = t >> 6;
    const int lane = t & 63;
    const int quad = lane >> 4;
    const int l16  = lane & 15;

    const int qbase = blockIdx.x * QT;
    const int strip = blockIdx.y;
    const int SS    = (N + NSTRIPS - 1) / NSTRIPS;
    const int n0    = strip * SS;
    const int nend  = (n0 + SS < N) ? (n0 + SS) : N;
    const int ntiles = (nend - n0 + NT - 1) / NT;

    // A fragments: wave's 16 query rows, K=256, resident in registers.
    short8 afrag[8];
    {
        int qrow = qbase + wave * 16 + l16;
        if (qrow < B) {
            const unsigned short* qp = q_bf16 + (size_t)qrow * DIM + quad * 8;
#pragma unroll
            for (int ks = 0; ks < 8; ks++)
                afrag[ks] = *(const short8*)(qp + ks * 32);
        } else {
#pragma unroll
            for (int ks = 0; ks < 8; ks++)
#pragma unroll
                for (int j = 0; j < 8; j++) afrag[ks][j] = 0;
        }
    }

    // per-thread top-8 (ascending) over subset: query = t&63, n%64 in [sub*16, sub*16+16)
    const int selq = t & 63;
    const int sub  = t >> 6;
    float ts[SUB_TOP]; int ti[SUB_TOP];
#pragma unroll
    for (int j = 0; j < SUB_TOP; j++) { ts[j] = -3e38f; ti[j] = 0; }

    const int l5  = lane >> 5;   // 0/1
    const int s32 = lane & 31;

    auto stage = [&](int tileIdx) {
        int base = n0 + tileIdx * NT;
        if (PRE) {
#pragma unroll
            for (int is = 0; is < 8; is++) {
                int rl = is * 8 + wave * 2 + l5;
                int n = base + rl; if (n >= nend) n = nend - 1;
                int chunk = s32 ^ (rl & 7);
                const unsigned short* gp = mem_bf16 + (size_t)n * DIM + chunk * 8;
                unsigned short* lp = lds_m + (is * 8 + wave * 2) * DIM;  // wave-uniform
                __builtin_amdgcn_global_load_lds((gbl_u32*)(const void*)gp,
                                                 (lds_u32*)(void*)lp, 16, 0, 0);
            }
        } else {
#pragma unroll 4
            for (int i = 0; i < 16; i++) {
                int rl = i * 4 + wave;
                int n = base + rl;
                ushort4 o;
                if (n < nend) {
                    float rinv = rnorm_mem[n];
                    float4 v = ((const float4*)(mem + (size_t)n * DIM))[lane];
                    o.x = f2bf(v.x * rinv); o.y = f2bf(v.y * rinv);
                    o.z = f2bf(v.z * rinv); o.w = f2bf(v.w * rinv);
                } else { o.x = 0; o.y = 0; o.z = 0; o.w = 0; }
                int slot = (lane >> 1) ^ (rl & 7);
                *(ushort4*)(lds_m + rl * DIM + slot * 8 + (lane & 1) * 4) = o;
            }
        }
    };

    stage(0);
    __syncthreads();

    const floatx4 zero4 = {0.f, 0.f, 0.f, 0.f};
    for (int tile = 0; tile < ntiles; tile++) {
        floatx4 acc[4];
#pragma unroll
        for (int nt = 0; nt < 4; nt++) acc[nt] = zero4;
#pragma unroll
        for (int ks = 0; ks < 8; ks++) {
#pragma unroll
            for (int nt = 0; nt < 4; nt++) {
                int row = nt * 16 + l16;
                int slot = (ks * 4 + quad) ^ (l16 & 7);
                short8 b = *(const short8*)(lds_m + row * DIM + slot * 8);
                acc[nt] = __builtin_amdgcn_mfma_f32_16x16x32_bf16(afrag[ks], b, acc[nt], 0, 0, 0);
            }
        }
        // C layout: col(lane&15)=n, row(quad*4+r)=q.  Store [n][q] so r-regs are contiguous.
#pragma unroll
        for (int nt = 0; nt < 4; nt++) {
            float4 o; o.x = acc[nt][0]; o.y = acc[nt][1]; o.z = acc[nt][2]; o.w = acc[nt][3];
            *(float4*)(lds_s + (nt * 16 + l16) * 68 + wave * 16 + quad * 4) = o;
        }
        __syncthreads();                     // scores visible; lds_m reads retired

        if (tile + 1 < ntiles) stage(tile + 1);  // overlaps with selection below

        int tbase = n0 + tile * NT;
#pragma unroll
        for (int i = 0; i < 16; i++) {
            int nl = sub * 16 + i;
            float s = lds_s[nl * 68 + selq];
            int idx = tbase + nl;
            if (s > ts[0] && idx < nend) {
#pragma unroll
                for (int j = 0; j < SUB_TOP; j++) {
                    if (j == SUB_TOP - 1) {
                        if (s > ts[j]) { ts[j] = s; ti[j] = idx; }
                    } else {
                        bool cn = s > ts[j + 1];
                        bool cj = s > ts[j];
                        float nv = cn ? ts[j + 1] : (cj ? s : ts[j]);
                        int   ni = cn ? ti[j + 1] : (cj ? idx : ti[j]);
                        ts[j] = nv; ti[j] = ni;
                    }
                }
            }
        }
        __syncthreads();                     // selection + staging drained
    }

    // merge: dump 4x8 per query into LDS (stride 33 = conflict-free), top-16 by one thread/query
    float* ms = lds_s;                   // [64][33] floats
    int*   mi = (int*)(lds_s + 64 * 33); // [64][33] ints  (total 16896 B <= 17408)
#pragma unroll
    for (int j = 0; j < SUB_TOP; j++) {
        ms[selq * 33 + sub * 8 + j] = ts[j];
        mi[selq * 33 + sub * 8 + j] = ti[j];
    }
    __syncthreads();

    if (t < QT) {
        float bs[STRIP_TOP]; int bi[STRIP_TOP];
#pragma unroll
        for (int j = 0; j < STRIP_TOP; j++) { bs[j] = -3e38f; bi[j] = 0; }
        for (int c = 0; c < 32; c++) {
            float s = ms[t * 33 + c];
            int idx = mi[t * 33 + c];
            if (s > bs[0]) {
#pragma unroll
                for (int j = 0; j < STRIP_TOP; j++) {
                    if (j == STRIP_TOP - 1) {
                        if (s > bs[j]) { bs[j] = s; bi[j] = idx; }
                    } else {
                        bool cn = s > bs[j + 1];
                        bool cj = s > bs[j];
                        float nv = cn ? bs[j + 1] : (cj ? s : bs[j]);
                        int   ni = cn ? bi[j + 1] : (cj ? idx : bi[j]);
                        bs[j] = nv; bi[j] = ni;
                    }
                }
            }
        }
        int gq = qbase + t;
        if (gq < B) {
            size_t off = ((size_t)gq * NSTRIPS + strip) * STRIP_TOP;
#pragma unroll
            for (int j = 0; j < STRIP_TOP; j++) {
                cand_score[off + j] = bs[j];
                cand_idx[off + j]   = bi[j];
            }
        }
    }
}

// ---------------- Kernel 3: wave-sync top-64 cut, fp64 rescore, top-8, gather ----------------
__global__ __launch_bounds__(256) void rescore_kernel(
    const float* __restrict__ query,
    const float* __restrict__ mem,
    const int* __restrict__ cand_idx,
    const float* __restrict__ cand_score,
    float* __restrict__ out,
    int B, int N)
{
    __shared__ float  cs[CAND];
    __shared__ int    ci[CAND];
    __shared__ float  lds_q[DIM];
    __shared__ double red[4];
    __shared__ double qss_sh;
    __shared__ int    sel_i[RESCORE];
    __shared__ double rs[RESCORE];
    __shared__ double best_s[TOPK];
    __shared__ int    best_i[TOPK];

    const int t    = threadIdx.x;
    const int q    = blockIdx.x;
    const int lane = t & 63;
    const int wave = t >> 6;

    for (int i = t; i < CAND; i += 256) {
        size_t off = (size_t)q * CAND + i;
        cs[i] = cand_score[off];
        ci[i] = cand_idx[off];
    }

    float qv = query[(size_t)q * DIM + t];
    lds_q[t] = qv;
    double p = (double)qv * (double)qv;
#pragma unroll
    for (int m = 32; m >= 1; m >>= 1) p += __shfl_xor(p, m, 64);
    if (lane == 0) red[wave] = p;
    __syncthreads();
    if (t == 0) qss_sh = red[0] + red[1] + red[2] + red[3];

    // per-wave bitonic sort (descending) of its 128-candidate quarter; wave-synchronous
    {
        float* qcs = cs + wave * 128;
        int*   qci = ci + wave * 128;
        for (int k = 2; k <= 128; k <<= 1) {
            for (int j = k >> 1; j > 0; j >>= 1) {
                int i  = 2 * lane - (lane & (j - 1));
                int ip = i + j;
                bool up = ((i & k) == 0);
                float s0 = qcs[i], s1 = qcs[ip];
                int   i0 = qci[i], i1 = qci[ip];
                bool aFirst = (s0 > s1) || (s0 == s1 && i0 < i1);
                bool doSwap = up ? (!aFirst) : aFirst;
                if (doSwap) { qcs[i] = s1; qci[i] = i1; qcs[ip] = s0; qci[ip] = i0; }
            }
        }
        if (lane < 16) sel_i[wave * 16 + lane] = qci[lane];   // per-wave top-16
    }
    __syncthreads();

    // fp64 exact cosine for the 64 selected; wave handles its 16, one at a time
    double qss = qss_sh;
    for (int r = 0; r < 16; r++) {
        int c = wave * 16 + r;
        int idx = sel_i[c];
        float4 mv = ((const float4*)(mem + (size_t)idx * DIM))[lane];
        float4 qv4 = ((const float4*)lds_q)[lane];
        double dqm = (double)mv.x * (double)qv4.x + (double)mv.y * (double)qv4.y
                   + (double)mv.z * (double)qv4.z + (double)mv.w * (double)qv4.w;
        double dmm = (double)mv.x * (double)mv.x + (double)mv.y * (double)mv.y
                   + (double)mv.z * (double)mv.z + (double)mv.w * (double)mv.w;
#pragma unroll
        for (int m = 32; m >= 1; m >>= 1) {
            dqm += __shfl_xor(dqm, m, 64);
            dmm += __shfl_xor(dmm, m, 64);
        }
        if (lane == 0)
            rs[c] = dqm / (fmax(sqrt(qss), 1e-12) * fmax(sqrt(dmm), 1e-12));
    }
    __syncthreads();

    if (t == 0) {   // serial exact top-8, tie-break (score desc, idx asc)
        double bs[TOPK]; int bi[TOPK];
        for (int i = 0; i < TOPK; i++) { bs[i] = -1e300; bi[i] = 0x7fffffff; }
        for (int c = 0; c < RESCORE; c++) {
            double s = rs[c]; int id = sel_i[c];
            bool better = (s > bs[TOPK - 1]) || (s == bs[TOPK - 1] && id < bi[TOPK - 1]);
            if (better) {
                int pos = TOPK - 1;
                while (pos > 0) {
                    bool b2 = (s > bs[pos - 1]) || (s == bs[pos - 1] && id < bi[pos - 1]);
                    if (!b2) break;
                    bs[pos] = bs[pos - 1]; bi[pos] = bi[pos - 1]; pos--;
                }
                bs[pos] = s; bi[pos] = id;
            }
        }
        for (int i = 0; i < TOPK; i++) { best_s[i] = bs[i]; best_i[i] = bi[i]; }
    }
    __syncthreads();

    size_t score_base = (size_t)B * TOPK * DIM;
    if (t < TOPK) out[score_base + (size_t)q * TOPK + t] = (float)best_s[t];

#pragma unroll
    for (int rep = 0; rep < 2; rep++) {
        int j  = t >> 5;
        int d4 = (t & 31) + rep * 32;
        int idx = best_i[j];
        float4 v = ((const float4*)(mem + (size_t)idx * DIM))[d4];
        ((float4*)(out + ((size_t)q * TOPK + j) * DIM))[d4] = v;
    }
}

extern "C" void kernel_launch(void* const* d_in, const int* in_sizes, int n_in,
                              void* d_out, int out_size, void* d_ws, size_t ws_size,
                              hipStream_t stream)
{
    const float* query = (const float*)d_in[0];
    const float* mem   = (const float*)d_in[1];
    int B = in_sizes[0] / DIM;
    int N = in_sizes[1] / DIM;

    auto align256 = [](size_t x) { return (x + 255) & ~(size_t)255; };
    size_t off = 0;
    auto alloc = [&](size_t bytes) { void* p = (char*)d_ws + off; off += align256(bytes); return p; };

    float* rnorm_mem       = (float*)alloc((size_t)N * 4);
    unsigned short* q_bf16 = (unsigned short*)alloc((size_t)B * DIM * 2);
    int* cand_idx          = (int*)alloc((size_t)B * CAND * 4);
    float* cand_score      = (float*)alloc((size_t)B * CAND * 4);
    size_t base_need = off;
    unsigned short* mem_bf16 = (unsigned short*)((char*)d_ws + base_need);
    bool pre = (base_need + align256((size_t)N * DIM * 2)) <= ws_size;
    if (!pre) mem_bf16 = nullptr;

    int prep_blocks = (N + B + 3) / 4;
    prep_kernel<<<prep_blocks, 256, 0, stream>>>(query, mem, rnorm_mem, q_bf16,
                                                 mem_bf16, B, N);

    dim3 g2((B + QT - 1) / QT, NSTRIPS);
    if (pre)
        score_select_kernel<true><<<g2, 256, 0, stream>>>(mem, rnorm_mem, mem_bf16, q_bf16,
                                                          cand_idx, cand_score, B, N);
    else
        score_select_kernel<false><<<g2, 256, 0, stream>>>(mem, rnorm_mem, mem_bf16, q_bf16,
                                                           cand_idx, cand_score, B, N);

    rescore_kernel<<<B, 256, 0, stream>>>(query, mem, cand_idx, cand_score,
                                          (float*)d_out, B, N);
}

// Round 3
// 434.284 us; speedup vs baseline: 6.7175x; 1.6392x over previous
//
#include <hip/hip_runtime.h>
#include <hip/hip_bf16.h>
#include <stdint.h>

#define DIM 256
#define TOPK 8
#define NSTRIPS 32
#define STRIP_TOP 16                 // candidates per (query,strip) = 2 threads x top-8
#define SUB_TOP 8
#define QT 128
#define NT 64
#define CAND (NSTRIPS * STRIP_TOP)   // 512
#define RESCORE 64
#define SSTRIDE 66                   // score LDS stride (floats)
#define IDXMASK 0x1FFFFu

typedef __attribute__((ext_vector_type(8))) short short8;
typedef __attribute__((ext_vector_type(4))) float floatx4;
typedef __attribute__((address_space(3))) unsigned int lds_u32;
typedef __attribute__((address_space(1))) const unsigned int gbl_u32;

__device__ __forceinline__ unsigned short f2bf(float f) {
    union { float f; uint32_t u; } v; v.f = f;
    uint32_t u = v.u;
    uint32_t r = u + 0x7fffu + ((u >> 16) & 1u);   // RNE
    return (unsigned short)(r >> 16);
}

__device__ __forceinline__ uint32_t umaxu(uint32_t a, uint32_t b) { return a > b ? a : b; }
__device__ __forceinline__ uint32_t uminu(uint32_t a, uint32_t b) { return a < b ? a : b; }

// ---------------- Kernel 1: norms + normalized bf16 copies ----------------
__global__ void prep_kernel(const float* __restrict__ query,
                            const float* __restrict__ mem,
                            float* __restrict__ rnorm_mem,
                            unsigned short* __restrict__ q_bf16,
                            unsigned short* __restrict__ mem_bf16,  // may be null
                            int B, int N)
{
    int wave = threadIdx.x >> 6;
    int lane = threadIdx.x & 63;
    int row  = blockIdx.x * 4 + wave;
    int total = N + B;
    if (row >= total) return;
    const float* src = (row < N) ? (mem + (size_t)row * DIM)
                                 : (query + (size_t)(row - N) * DIM);
    float4 v = ((const float4*)src)[lane];
    float ss = v.x * v.x + v.y * v.y + v.z * v.z + v.w * v.w;
#pragma unroll
    for (int m = 32; m >= 1; m >>= 1) ss += __shfl_xor(ss, m, 64);
    float rinv = 1.0f / fmaxf(sqrtf(ss), 1e-12f);
    ushort4 o;
    o.x = f2bf(v.x * rinv); o.y = f2bf(v.y * rinv);
    o.z = f2bf(v.z * rinv); o.w = f2bf(v.w * rinv);
    if (row < N) {
        if (lane == 0) rnorm_mem[row] = rinv;
        if (mem_bf16) ((ushort4*)(mem_bf16 + (size_t)row * DIM))[lane] = o;
    } else {
        ((ushort4*)(q_bf16 + (size_t)(row - N) * DIM))[lane] = o;
    }
}

// ---------------- Kernel 2: bf16-MFMA scoring (A-reuse=2) + key-packed top-k ----------------
template<bool PRE>
__global__ __launch_bounds__(256, 2) void score_select_kernel(
    const float* __restrict__ mem,
    const float* __restrict__ rnorm_mem,
    const unsigned short* __restrict__ mem_bf16,
    const unsigned short* __restrict__ q_bf16,
    uint32_t* __restrict__ cand_key,
    int B, int N)
{
    __shared__ unsigned short lds_m[NT * DIM];     // 32768 B, XOR-swizzled rows
    __shared__ float lds_s[QT * SSTRIDE];          // 33792 B, [q][n] stride 66

    const int t    = threadIdx.x;
    const int wave = t >> 6;
    const int lane = t & 63;
    const int quad = lane >> 4;
    const int l16  = lane & 15;

    const int qbase = blockIdx.x * QT;
    const int strip = blockIdx.y;
    const int SS    = (N + NSTRIPS - 1) / NSTRIPS;
    const int n0    = strip * SS;
    const int nend  = (n0 + SS < N) ? (n0 + SS) : N;
    const int ntiles = (nend - n0 + NT - 1) / NT;

    // Two A-sets per wave: q rows  qbase + s*64 + wave*16 + l16,  full K=256.
    short8 afrag[2][8];
#pragma unroll
    for (int s = 0; s < 2; s++) {
        int qrow = qbase + s * 64 + wave * 16 + l16;
        const unsigned short* qp = q_bf16 + (size_t)qrow * DIM + quad * 8;
#pragma unroll
        for (int ks = 0; ks < 8; ks++)
            afrag[s][ks] = *(const short8*)(qp + ks * 32);
    }

    // per-thread top-8 keys (ascending), subset: q = t&127, n in [sub*32, sub*32+32)
    const int selq = t & 127;
    const int sub  = t >> 7;
    uint32_t ts[SUB_TOP];
#pragma unroll
    for (int j = 0; j < SUB_TOP; j++) ts[j] = 0;

    const int l5  = lane >> 5;   // 0/1
    const int s32 = lane & 31;

    auto stage = [&](int tileIdx) {
        int base = n0 + tileIdx * NT;
        if (PRE) {
#pragma unroll
            for (int is = 0; is < 8; is++) {
                int rl = is * 8 + wave * 2 + l5;
                int n = base + rl; if (n >= nend) n = nend - 1;
                int chunk = s32 ^ (rl & 7);
                const unsigned short* gp = mem_bf16 + (size_t)n * DIM + chunk * 8;
                unsigned short* lp = lds_m + (is * 8 + wave * 2) * DIM;  // wave-uniform
                __builtin_amdgcn_global_load_lds((gbl_u32*)(const void*)gp,
                                                 (lds_u32*)(void*)lp, 16, 0, 0);
            }
        } else {
#pragma unroll 4
            for (int i = 0; i < 16; i++) {
                int rl = i * 4 + wave;
                int n = base + rl;
                ushort4 o;
                if (n < nend) {
                    float rinv = rnorm_mem[n];
                    float4 v = ((const float4*)(mem + (size_t)n * DIM))[lane];
                    o.x = f2bf(v.x * rinv); o.y = f2bf(v.y * rinv);
                    o.z = f2bf(v.z * rinv); o.w = f2bf(v.w * rinv);
                } else { o.x = 0; o.y = 0; o.z = 0; o.w = 0; }
                int slot = (lane >> 1) ^ (rl & 7);
                *(ushort4*)(lds_m + rl * DIM + slot * 8 + (lane & 1) * 4) = o;
            }
        }
    };

    stage(0);
    __syncthreads();

    const floatx4 zero4 = {0.f, 0.f, 0.f, 0.f};
    for (int tile = 0; tile < ntiles; tile++) {
        floatx4 acc[2][4];
#pragma unroll
        for (int s = 0; s < 2; s++)
#pragma unroll
            for (int nt = 0; nt < 4; nt++) acc[s][nt] = zero4;

#pragma unroll
        for (int ks = 0; ks < 8; ks++) {
#pragma unroll
            for (int nt = 0; nt < 4; nt++) {
                int row = nt * 16 + l16;
                int slot = (ks * 4 + quad) ^ (l16 & 7);
                short8 b = *(const short8*)(lds_m + row * DIM + slot * 8);
                acc[0][nt] = __builtin_amdgcn_mfma_f32_16x16x32_bf16(afrag[0][ks], b, acc[0][nt], 0, 0, 0);
                acc[1][nt] = __builtin_amdgcn_mfma_f32_16x16x32_bf16(afrag[1][ks], b, acc[1][nt], 0, 0, 0);
            }
        }
        // C layout: col(lane&15)=n, row(quad*4+r)=q.  Per-reg b32 stores to [q][66] (<=2-way banks).
#pragma unroll
        for (int s = 0; s < 2; s++)
#pragma unroll
            for (int nt = 0; nt < 4; nt++) {
                int qrow = s * 64 + wave * 16 + quad * 4;
                int col  = nt * 16 + l16;
#pragma unroll
                for (int r = 0; r < 4; r++)
                    lds_s[(qrow + r) * SSTRIDE + col] = acc[s][nt][r];
            }
        __syncthreads();                     // scores visible; lds_m reads retired

        if (tile + 1 < ntiles) stage(tile + 1);  // overlaps with selection below

        int tbase = n0 + tile * NT;
        const float* sp = lds_s + selq * SSTRIDE + sub * 32;
#pragma unroll
        for (int c4 = 0; c4 < 8; c4++) {
            float4 v = *(const float4*)(sp + c4 * 4);
#pragma unroll
            for (int e = 0; e < 4; e++) {
                float s = (e == 0) ? v.x : (e == 1) ? v.y : (e == 2) ? v.z : v.w;
                int gidx = tbase + sub * 32 + c4 * 4 + e;
                uint32_t u = __float_as_uint(s);
                uint32_t mono = u ^ ((uint32_t)(((int32_t)u) >> 31) | 0x80000000u);
                uint32_t key = (mono & 0xFFFE0000u) | (uint32_t)gidx;
                if (gidx < nend && key > ts[0]) {
#pragma unroll
                    for (int j = 0; j < SUB_TOP - 1; j++)
                        ts[j] = uminu(umaxu(ts[j], key), ts[j + 1]);
                    ts[SUB_TOP - 1] = umaxu(ts[SUB_TOP - 1], key);
                }
            }
        }
        __syncthreads();                     // selection + staging drained
    }

    // write candidates: per (q,strip): 2 threads x 8 keys = 16
    size_t off = ((size_t)(qbase + selq) * NSTRIPS + strip) * STRIP_TOP + sub * SUB_TOP;
#pragma unroll
    for (int j = 0; j < SUB_TOP; j++)
        cand_key[off + j] = ts[j];
}

// ---------------- Kernel 3: key sort, top-64 cut, fp64 rescore, top-8, gather ----------------
__global__ __launch_bounds__(256) void rescore_kernel(
    const float* __restrict__ query,
    const float* __restrict__ mem,
    const uint32_t* __restrict__ cand_key,
    float* __restrict__ out,
    int B, int N)
{
    __shared__ uint32_t cs[CAND];
    __shared__ float  lds_q[DIM];
    __shared__ double red[4];
    __shared__ double qss_sh;
    __shared__ int    sel_i[RESCORE];
    __shared__ double rs[RESCORE];
    __shared__ double best_s[TOPK];
    __shared__ int    best_i[TOPK];

    const int t    = threadIdx.x;
    const int q    = blockIdx.x;
    const int lane = t & 63;
    const int wave = t >> 6;

    for (int i = t; i < CAND; i += 256)
        cs[i] = cand_key[(size_t)q * CAND + i];

    float qv = query[(size_t)q * DIM + t];
    lds_q[t] = qv;
    double p = (double)qv * (double)qv;
#pragma unroll
    for (int m = 32; m >= 1; m >>= 1) p += __shfl_xor(p, m, 64);
    if (lane == 0) red[wave] = p;
    __syncthreads();
    if (t == 0) qss_sh = red[0] + red[1] + red[2] + red[3];

    // per-wave bitonic sort (descending) of its 128-key quarter; wave-synchronous
    {
        uint32_t* qcs = cs + wave * 128;
        for (int k = 2; k <= 128; k <<= 1) {
            for (int j = k >> 1; j > 0; j >>= 1) {
                int i  = 2 * lane - (lane & (j - 1));
                int ip = i + j;
                bool up = ((i & k) == 0);
                uint32_t a = qcs[i], b2 = qcs[ip];
                bool aFirst = a > b2;
                bool doSwap = up ? (!aFirst) : aFirst;
                if (doSwap) { qcs[i] = b2; qcs[ip] = a; }
            }
        }
        if (lane < 16) sel_i[wave * 16 + lane] = (int)(qcs[lane] & IDXMASK);
    }
    __syncthreads();

    // fp64 exact cosine for the 64 selected; each wave handles its 16
    double qss = qss_sh;
    for (int r = 0; r < 16; r++) {
        int c = wave * 16 + r;
        int idx = sel_i[c];
        float4 mv = ((const float4*)(mem + (size_t)idx * DIM))[lane];
        float4 qv4 = ((const float4*)lds_q)[lane];
        double dqm = (double)mv.x * (double)qv4.x + (double)mv.y * (double)qv4.y
                   + (double)mv.z * (double)qv4.z + (double)mv.w * (double)qv4.w;
        double dmm = (double)mv.x * (double)mv.x + (double)mv.y * (double)mv.y
                   + (double)mv.z * (double)mv.z + (double)mv.w * (double)mv.w;
#pragma unroll
        for (int m = 32; m >= 1; m >>= 1) {
            dqm += __shfl_xor(dqm, m, 64);
            dmm += __shfl_xor(dmm, m, 64);
        }
        if (lane == 0)
            rs[c] = dqm / (fmax(sqrt(qss), 1e-12) * fmax(sqrt(dmm), 1e-12));
    }
    __syncthreads();

    if (t == 0) {   // serial exact top-8, tie-break (score desc, idx asc)
        double bs[TOPK]; int bi[TOPK];
        for (int i = 0; i < TOPK; i++) { bs[i] = -1e300; bi[i] = 0x7fffffff; }
        for (int c = 0; c < RESCORE; c++) {
            double s = rs[c]; int id = sel_i[c];
            bool better = (s > bs[TOPK - 1]) || (s == bs[TOPK - 1] && id < bi[TOPK - 1]);
            if (better) {
                int pos = TOPK - 1;
                while (pos > 0) {
                    bool b2 = (s > bs[pos - 1]) || (s == bs[pos - 1] && id < bi[pos - 1]);
                    if (!b2) break;
                    bs[pos] = bs[pos - 1]; bi[pos] = bi[pos - 1]; pos--;
                }
                bs[pos] = s; bi[pos] = id;
            }
        }
        for (int i = 0; i < TOPK; i++) { best_s[i] = bs[i]; best_i[i] = bi[i]; }
    }
    __syncthreads();

    size_t score_base = (size_t)B * TOPK * DIM;
    if (t < TOPK) out[score_base + (size_t)q * TOPK + t] = (float)best_s[t];

#pragma unroll
    for (int rep = 0; rep < 2; rep++) {
        int j  = t >> 5;
        int d4 = (t & 31) + rep * 32;
        int idx = best_i[j];
        float4 v = ((const float4*)(mem + (size_t)idx * DIM))[d4];
        ((float4*)(out + ((size_t)q * TOPK + j) * DIM))[d4] = v;
    }
}

extern "C" void kernel_launch(void* const* d_in, const int* in_sizes, int n_in,
                              void* d_out, int out_size, void* d_ws, size_t ws_size,
                              hipStream_t stream)
{
    const float* query = (const float*)d_in[0];
    const float* mem   = (const float*)d_in[1];
    int B = in_sizes[0] / DIM;
    int N = in_sizes[1] / DIM;

    auto align256 = [](size_t x) { return (x + 255) & ~(size_t)255; };
    size_t off = 0;
    auto alloc = [&](size_t bytes) { void* p = (char*)d_ws + off; off += align256(bytes); return p; };

    float* rnorm_mem       = (float*)alloc((size_t)N * 4);
    unsigned short* q_bf16 = (unsigned short*)alloc((size_t)B * DIM * 2);
    uint32_t* cand_key     = (uint32_t*)alloc((size_t)B * CAND * 4);
    size_t base_need = off;
    unsigned short* mem_bf16 = (unsigned short*)((char*)d_ws + base_need);
    bool pre = (base_need + align256((size_t)N * DIM * 2)) <= ws_size;
    if (!pre) mem_bf16 = nullptr;

    int prep_blocks = (N + B + 3) / 4;
    prep_kernel<<<prep_blocks, 256, 0, stream>>>(query, mem, rnorm_mem, q_bf16,
                                                 mem_bf16, B, N);

    dim3 g2((B + QT - 1) / QT, NSTRIPS);
    if (pre)
        score_select_kernel<true><<<g2, 256, 0, stream>>>(mem, rnorm_mem, mem_bf16, q_bf16,
                                                          cand_key, B, N);
    else
        score_select_kernel<false><<<g2, 256, 0, stream>>>(mem, rnorm_mem, mem_bf16, q_bf16,
                                                           cand_key, B, N);

    rescore_kernel<<<B, 256, 0, stream>>>(query, mem, cand_key, (float*)d_out, B, N);
}

// Round 4
// 421.064 us; speedup vs baseline: 6.9284x; 1.0314x over previous
//
#include <hip/hip_runtime.h>
#include <hip/hip_bf16.h>
#include <stdint.h>

#define DIM 256
#define TOPK 8
#define NSTRIPS 64
#define STRIP_TOP 8                  // per (query,strip) top-8, one thread each
#define QT 256
#define NT 64
#define CAND (NSTRIPS * STRIP_TOP)   // 512
#define RESCORE 64
#define SLOTS 33                     // u32 row stride for packed scores
#define IDXMASK 0x1FFFFu

typedef __attribute__((ext_vector_type(8))) short short8;
typedef __attribute__((ext_vector_type(4))) float floatx4;
typedef __attribute__((address_space(3))) unsigned int lds_u32;
typedef __attribute__((address_space(1))) const unsigned int gbl_u32;

__device__ __forceinline__ unsigned short f2bf(float f) {
    union { float f; uint32_t u; } v; v.f = f;
    uint32_t u = v.u;
    uint32_t r = u + 0x7fffu + ((u >> 16) & 1u);   // RNE
    return (unsigned short)(r >> 16);
}

__device__ __forceinline__ uint32_t umaxu(uint32_t a, uint32_t b) { return a > b ? a : b; }
__device__ __forceinline__ uint32_t uminu(uint32_t a, uint32_t b) { return a < b ? a : b; }

// monotone 16-bit key of an f32 (truncated monotone u32 map: sign+exp+7 mantissa)
__device__ __forceinline__ uint32_t mono16(float f) {
    uint32_t u = __float_as_uint(f);
    uint32_t m = u ^ ((uint32_t)(((int32_t)u) >> 31) | 0x80000000u);
    return m >> 16;
}

// ---------------- Kernel 1: norms + normalized bf16 copies ----------------
__global__ void prep_kernel(const float* __restrict__ query,
                            const float* __restrict__ mem,
                            float* __restrict__ rnorm_mem,
                            unsigned short* __restrict__ q_bf16,
                            unsigned short* __restrict__ mem_bf16,  // may be null
                            int B, int N)
{
    int wave = threadIdx.x >> 6;
    int lane = threadIdx.x & 63;
    int row  = blockIdx.x * 4 + wave;
    int total = N + B;
    if (row >= total) return;
    const float* src = (row < N) ? (mem + (size_t)row * DIM)
                                 : (query + (size_t)(row - N) * DIM);
    float4 v = ((const float4*)src)[lane];
    float ss = v.x * v.x + v.y * v.y + v.z * v.z + v.w * v.w;
#pragma unroll
    for (int m = 32; m >= 1; m >>= 1) ss += __shfl_xor(ss, m, 64);
    float rinv = 1.0f / fmaxf(sqrtf(ss), 1e-12f);
    ushort4 o;
    o.x = f2bf(v.x * rinv); o.y = f2bf(v.y * rinv);
    o.z = f2bf(v.z * rinv); o.w = f2bf(v.w * rinv);
    if (row < N) {
        if (lane == 0) rnorm_mem[row] = rinv;
        if (mem_bf16) ((ushort4*)(mem_bf16 + (size_t)row * DIM))[lane] = o;
    } else {
        ((ushort4*)(q_bf16 + (size_t)(row - N) * DIM))[lane] = o;
    }
}

// ---------------- Kernel 2: bf16-MFMA scoring (A-reuse=4) + packed-key top-8 ----------------
template<bool PRE>
__global__ __launch_bounds__(256, 2) void score_select_kernel(
    const float* __restrict__ mem,
    const float* __restrict__ rnorm_mem,
    const unsigned short* __restrict__ mem_bf16,
    const unsigned short* __restrict__ q_bf16,
    uint32_t* __restrict__ cand_key,
    int B, int N)
{
    __shared__ unsigned short lds_m[NT * DIM];     // 32768 B, XOR-swizzled rows
    __shared__ uint32_t lds_s[QT * SLOTS];         // 33792 B: [q][slot j] = (lo=col j, hi=col j+32)

    const int t    = threadIdx.x;
    const int wave = t >> 6;
    const int lane = t & 63;
    const int quad = lane >> 4;
    const int l16  = lane & 15;

    const int qbase = blockIdx.x * QT;
    const int strip = blockIdx.y;
    const int SS    = (N + NSTRIPS - 1) / NSTRIPS;
    const int n0    = strip * SS;
    const int nend  = (n0 + SS < N) ? (n0 + SS) : N;
    const int limit = nend - n0;                    // valid strip-local rows
    const int ntiles = (limit + NT - 1) / NT;

    // Four A-sets per wave: q rows  qbase + s*64 + wave*16 + l16,  full K=256.
    short8 afrag[4][8];
#pragma unroll
    for (int s = 0; s < 4; s++) {
        int qrow = qbase + s * 64 + wave * 16 + l16;
        const unsigned short* qp = q_bf16 + (size_t)qrow * DIM + quad * 8;
#pragma unroll
        for (int ks = 0; ks < 8; ks++)
            afrag[s][ks] = *(const short8*)(qp + ks * 32);
    }

    // per-thread top-8 keys (ascending); thread t owns query qbase+t, all columns
    uint32_t ts[STRIP_TOP];
#pragma unroll
    for (int j = 0; j < STRIP_TOP; j++) ts[j] = 0;

    const int l5  = lane >> 5;   // 0/1
    const int s32 = lane & 31;

    auto stage = [&](int tileIdx) {
        int base = n0 + tileIdx * NT;
        if (PRE) {
#pragma unroll
            for (int is = 0; is < 8; is++) {
                int rl = is * 8 + wave * 2 + l5;
                int n = base + rl; if (n >= nend) n = nend - 1;
                int chunk = s32 ^ (rl & 7);
                const unsigned short* gp = mem_bf16 + (size_t)n * DIM + chunk * 8;
                unsigned short* lp = lds_m + (is * 8 + wave * 2) * DIM;  // wave-uniform
                __builtin_amdgcn_global_load_lds((gbl_u32*)(const void*)gp,
                                                 (lds_u32*)(void*)lp, 16, 0, 0);
            }
        } else {
#pragma unroll 4
            for (int i = 0; i < 16; i++) {
                int rl = i * 4 + wave;
                int n = base + rl;
                ushort4 o;
                if (n < nend) {
                    float rinv = rnorm_mem[n];
                    float4 v = ((const float4*)(mem + (size_t)n * DIM))[lane];
                    o.x = f2bf(v.x * rinv); o.y = f2bf(v.y * rinv);
                    o.z = f2bf(v.z * rinv); o.w = f2bf(v.w * rinv);
                } else { o.x = 0; o.y = 0; o.z = 0; o.w = 0; }
                int slot = (lane >> 1) ^ (rl & 7);
                *(ushort4*)(lds_m + rl * DIM + slot * 8 + (lane & 1) * 4) = o;
            }
        }
    };

    stage(0);
    __syncthreads();

    const floatx4 zero4 = {0.f, 0.f, 0.f, 0.f};
    for (int tile = 0; tile < ntiles; tile++) {
        floatx4 acc[4][4];
#pragma unroll
        for (int s = 0; s < 4; s++)
#pragma unroll
            for (int nt = 0; nt < 4; nt++) acc[s][nt] = zero4;

#pragma unroll
        for (int ks = 0; ks < 8; ks++) {
#pragma unroll
            for (int nt = 0; nt < 4; nt++) {
                int row = nt * 16 + l16;
                int slot = (ks * 4 + quad) ^ (l16 & 7);
                short8 b = *(const short8*)(lds_m + row * DIM + slot * 8);
#pragma unroll
                for (int s = 0; s < 4; s++)
                    acc[s][nt] = __builtin_amdgcn_mfma_f32_16x16x32_bf16(afrag[s][ks], b, acc[s][nt], 0, 0, 0);
            }
        }
        // C layout: col(lane&15)=n, row(quad*4+r)=q.
        // Pack (col j, col j+32) as two mono16 halves into u32 slot j of row q.
#pragma unroll
        for (int s = 0; s < 4; s++) {
            int qrow = s * 64 + wave * 16 + quad * 4;
#pragma unroll
            for (int r = 0; r < 4; r++) {
                uint32_t p02 = mono16(acc[s][0][r]) | (mono16(acc[s][2][r]) << 16);
                uint32_t p13 = mono16(acc[s][1][r]) | (mono16(acc[s][3][r]) << 16);
                lds_s[(qrow + r) * SLOTS + l16]      = p02;   // cols l16, l16+32
                lds_s[(qrow + r) * SLOTS + 16 + l16] = p13;   // cols 16+l16, 48+l16
            }
        }
        __syncthreads();                     // scores visible; lds_m reads retired

        if (tile + 1 < ntiles) stage(tile + 1);  // overlaps with selection below

        // selection: thread t = query, 64 cols via 32 packed u32; key = score16<<16 | loc
        const int tloc = tile * NT;
        const uint4* sp = (const uint4*)(lds_s + t * SLOTS);
        bool full = (tloc + NT <= limit);
#pragma unroll
        for (int j4 = 0; j4 < 8; j4++) {
            uint4 v4 = sp[j4];
#pragma unroll
            for (int e = 0; e < 4; e++) {
                uint32_t v = (e == 0) ? v4.x : (e == 1) ? v4.y : (e == 2) ? v4.z : v4.w;
                int j = j4 * 4 + e;
                uint32_t key_lo = (v << 16) | (uint32_t)(tloc + j);
                uint32_t key_hi = (v & 0xFFFF0000u) | (uint32_t)(tloc + j + 32);
                if (!full) {
                    if (tloc + j >= limit)      key_lo = 0;
                    if (tloc + j + 32 >= limit) key_hi = 0;
                }
                if (key_lo > ts[0]) {
#pragma unroll
                    for (int j2 = 0; j2 < STRIP_TOP - 1; j2++)
                        ts[j2] = uminu(umaxu(ts[j2], key_lo), ts[j2 + 1]);
                    ts[STRIP_TOP - 1] = umaxu(ts[STRIP_TOP - 1], key_lo);
                }
                if (key_hi > ts[0]) {
#pragma unroll
                    for (int j2 = 0; j2 < STRIP_TOP - 1; j2++)
                        ts[j2] = uminu(umaxu(ts[j2], key_hi), ts[j2 + 1]);
                    ts[STRIP_TOP - 1] = umaxu(ts[STRIP_TOP - 1], key_hi);
                }
            }
        }
        __syncthreads();                     // selection + staging drained
    }

    // write candidates, converting to (score15 << 17 | gidx17) — R3's proven key format
    size_t off = ((size_t)(qbase + t) * NSTRIPS + strip) * STRIP_TOP;
#pragma unroll
    for (int j = 0; j < STRIP_TOP; j++) {
        uint32_t k = ts[j];
        uint32_t loc = k & 0xFFFFu;
        uint32_t key2 = ((k >> 17) << 17) | (uint32_t)(n0 + (int)loc);
        cand_key[off + j] = key2;
    }
}

// ---------------- Kernel 3: key sort, top-64 cut, fp64 rescore, top-8, gather ----------------
__global__ __launch_bounds__(256) void rescore_kernel(
    const float* __restrict__ query,
    const float* __restrict__ mem,
    const uint32_t* __restrict__ cand_key,
    float* __restrict__ out,
    int B, int N)
{
    __shared__ uint32_t cs[CAND];
    __shared__ float  lds_q[DIM];
    __shared__ double red[4];
    __shared__ double qss_sh;
    __shared__ int    sel_i[RESCORE];
    __shared__ double rs[RESCORE];
    __shared__ double best_s[TOPK];
    __shared__ int    best_i[TOPK];

    const int t    = threadIdx.x;
    const int q    = blockIdx.x;
    const int lane = t & 63;
    const int wave = t >> 6;

    for (int i = t; i < CAND; i += 256)
        cs[i] = cand_key[(size_t)q * CAND + i];

    float qv = query[(size_t)q * DIM + t];
    lds_q[t] = qv;
    double p = (double)qv * (double)qv;
#pragma unroll
    for (int m = 32; m >= 1; m >>= 1) p += __shfl_xor(p, m, 64);
    if (lane == 0) red[wave] = p;
    __syncthreads();
    if (t == 0) qss_sh = red[0] + red[1] + red[2] + red[3];

    // per-wave bitonic sort (descending) of its 128-key quarter; wave-synchronous
    {
        uint32_t* qcs = cs + wave * 128;
        for (int k = 2; k <= 128; k <<= 1) {
            for (int j = k >> 1; j > 0; j >>= 1) {
                int i  = 2 * lane - (lane & (j - 1));
                int ip = i + j;
                bool up = ((i & k) == 0);
                uint32_t a = qcs[i], b2 = qcs[ip];
                bool aFirst = a > b2;
                bool doSwap = up ? (!aFirst) : aFirst;
                if (doSwap) { qcs[i] = b2; qcs[ip] = a; }
            }
        }
        if (lane < 16) sel_i[wave * 16 + lane] = (int)(qcs[lane] & IDXMASK);
    }
    __syncthreads();

    // fp64 exact cosine for the 64 selected; each wave handles its 16
    double qss = qss_sh;
    for (int r = 0; r < 16; r++) {
        int c = wave * 16 + r;
        int idx = sel_i[c];
        float4 mv = ((const float4*)(mem + (size_t)idx * DIM))[lane];
        float4 qv4 = ((const float4*)lds_q)[lane];
        double dqm = (double)mv.x * (double)qv4.x + (double)mv.y * (double)qv4.y
                   + (double)mv.z * (double)qv4.z + (double)mv.w * (double)qv4.w;
        double dmm = (double)mv.x * (double)mv.x + (double)mv.y * (double)mv.y
                   + (double)mv.z * (double)mv.z + (double)mv.w * (double)mv.w;
#pragma unroll
        for (int m = 32; m >= 1; m >>= 1) {
            dqm += __shfl_xor(dqm, m, 64);
            dmm += __shfl_xor(dmm, m, 64);
        }
        if (lane == 0)
            rs[c] = dqm / (fmax(sqrt(qss), 1e-12) * fmax(sqrt(dmm), 1e-12));
    }
    __syncthreads();

    if (t == 0) {   // serial exact top-8, tie-break (score desc, idx asc)
        double bs[TOPK]; int bi[TOPK];
        for (int i = 0; i < TOPK; i++) { bs[i] = -1e300; bi[i] = 0x7fffffff; }
        for (int c = 0; c < RESCORE; c++) {
            double s = rs[c]; int id = sel_i[c];
            bool better = (s > bs[TOPK - 1]) || (s == bs[TOPK - 1] && id < bi[TOPK - 1]);
            if (better) {
                int pos = TOPK - 1;
                while (pos > 0) {
                    bool b2 = (s > bs[pos - 1]) || (s == bs[pos - 1] && id < bi[pos - 1]);
                    if (!b2) break;
                    bs[pos] = bs[pos - 1]; bi[pos] = bi[pos - 1]; pos--;
                }
                bs[pos] = s; bi[pos] = id;
            }
        }
        for (int i = 0; i < TOPK; i++) { best_s[i] = bs[i]; best_i[i] = bi[i]; }
    }
    __syncthreads();

    size_t score_base = (size_t)B * TOPK * DIM;
    if (t < TOPK) out[score_base + (size_t)q * TOPK + t] = (float)best_s[t];

#pragma unroll
    for (int rep = 0; rep < 2; rep++) {
        int j  = t >> 5;
        int d4 = (t & 31) + rep * 32;
        int idx = best_i[j];
        float4 v = ((const float4*)(mem + (size_t)idx * DIM))[d4];
        ((float4*)(out + ((size_t)q * TOPK + j) * DIM))[d4] = v;
    }
}

extern "C" void kernel_launch(void* const* d_in, const int* in_sizes, int n_in,
                              void* d_out, int out_size, void* d_ws, size_t ws_size,
                              hipStream_t stream)
{
    const float* query = (const float*)d_in[0];
    const float* mem   = (const float*)d_in[1];
    int B = in_sizes[0] / DIM;
    int N = in_sizes[1] / DIM;

    auto align256 = [](size_t x) { return (x + 255) & ~(size_t)255; };
    size_t off = 0;
    auto alloc = [&](size_t bytes) { void* p = (char*)d_ws + off; off += align256(bytes); return p; };

    float* rnorm_mem       = (float*)alloc((size_t)N * 4);
    unsigned short* q_bf16 = (unsigned short*)alloc((size_t)B * DIM * 2);
    uint32_t* cand_key     = (uint32_t*)alloc((size_t)B * CAND * 4);
    size_t base_need = off;
    unsigned short* mem_bf16 = (unsigned short*)((char*)d_ws + base_need);
    bool pre = (base_need + align256((size_t)N * DIM * 2)) <= ws_size;
    if (!pre) mem_bf16 = nullptr;

    int prep_blocks = (N + B + 3) / 4;
    prep_kernel<<<prep_blocks, 256, 0, stream>>>(query, mem, rnorm_mem, q_bf16,
                                                 mem_bf16, B, N);

    dim3 g2((B + QT - 1) / QT, NSTRIPS);
    if (pre)
        score_select_kernel<true><<<g2, 256, 0, stream>>>(mem, rnorm_mem, mem_bf16, q_bf16,
                                                          cand_key, B, N);
    else
        score_select_kernel<false><<<g2, 256, 0, stream>>>(mem, rnorm_mem, mem_bf16, q_bf16,
                                                           cand_key, B, N);

    rescore_kernel<<<B, 256, 0, stream>>>(query, mem, cand_key, (float*)d_out, B, N);
}

// Round 5
// 412.431 us; speedup vs baseline: 7.0734x; 1.0209x over previous
//
#include <hip/hip_runtime.h>
#include <hip/hip_bf16.h>
#include <stdint.h>

#define DIM 256
#define TOPK 8
#define NSTRIPS 64
#define STRIP_TOP 8                  // per (query,strip) top-8, one thread each
#define QT 256
#define NT 64
#define CAND (NSTRIPS * STRIP_TOP)   // 512
#define RESCORE 64
#define SLOTS 33                     // u32 row stride for packed scores
#define IDXMASK 0x1FFFFu

typedef __attribute__((ext_vector_type(8))) short short8;
typedef __attribute__((ext_vector_type(4))) float floatx4;
typedef __attribute__((address_space(3))) unsigned int lds_u32;
typedef __attribute__((address_space(1))) const unsigned int gbl_u32;

__device__ __forceinline__ unsigned short f2bf(float f) {
    union { float f; uint32_t u; } v; v.f = f;
    uint32_t u = v.u;
    uint32_t r = u + 0x7fffu + ((u >> 16) & 1u);   // RNE
    return (unsigned short)(r >> 16);
}

__device__ __forceinline__ uint32_t umaxu(uint32_t a, uint32_t b) { return a > b ? a : b; }
__device__ __forceinline__ uint32_t uminu(uint32_t a, uint32_t b) { return a < b ? a : b; }

// sorted-ascending top-8 insert: new[j] = med3(old[j], old[j+1], key); new[7]=max
__device__ __forceinline__ void top8_insert(uint32_t* ts, uint32_t key) {
#pragma unroll
    for (int j = 0; j < STRIP_TOP - 1; j++) {
        uint32_t m;
        asm("v_med3_u32 %0, %1, %2, %3" : "=v"(m) : "v"(ts[j]), "v"(ts[j + 1]), "v"(key));
        ts[j] = m;
    }
    ts[STRIP_TOP - 1] = umaxu(ts[STRIP_TOP - 1], key);
}

// ---------------- Kernel 1: norms + normalized bf16 copies ----------------
__global__ void prep_kernel(const float* __restrict__ query,
                            const float* __restrict__ mem,
                            float* __restrict__ rnorm_mem,
                            unsigned short* __restrict__ q_bf16,
                            unsigned short* __restrict__ mem_bf16,  // may be null
                            int B, int N)
{
    int wave = threadIdx.x >> 6;
    int lane = threadIdx.x & 63;
    int row  = blockIdx.x * 4 + wave;
    int total = N + B;
    if (row >= total) return;
    const float* src = (row < N) ? (mem + (size_t)row * DIM)
                                 : (query + (size_t)(row - N) * DIM);
    float4 v = ((const float4*)src)[lane];
    float ss = v.x * v.x + v.y * v.y + v.z * v.z + v.w * v.w;
#pragma unroll
    for (int m = 32; m >= 1; m >>= 1) ss += __shfl_xor(ss, m, 64);
    float rinv = 1.0f / fmaxf(sqrtf(ss), 1e-12f);
    ushort4 o;
    o.x = f2bf(v.x * rinv); o.y = f2bf(v.y * rinv);
    o.z = f2bf(v.z * rinv); o.w = f2bf(v.w * rinv);
    if (row < N) {
        if (lane == 0) rnorm_mem[row] = rinv;
        if (mem_bf16) ((ushort4*)(mem_bf16 + (size_t)row * DIM))[lane] = o;
    } else {
        ((ushort4*)(q_bf16 + (size_t)(row - N) * DIM))[lane] = o;
    }
}

// ---------------- Kernel 2: bf16-MFMA scoring (A-reuse=4, biased keys) + gated top-8 ----------------
template<bool PRE>
__global__ __launch_bounds__(256, 2) void score_select_kernel(
    const float* __restrict__ mem,
    const float* __restrict__ rnorm_mem,
    const unsigned short* __restrict__ mem_bf16,
    const unsigned short* __restrict__ q_bf16,
    uint32_t* __restrict__ cand_key,
    int B, int N)
{
    __shared__ unsigned short lds_m[NT * DIM];     // 32768 B, XOR-swizzled rows
    __shared__ uint32_t lds_s[QT * SLOTS];         // 33792 B: [q][slot j] = (lo=col j, hi=col j+32)

    const int t    = threadIdx.x;
    const int wave = t >> 6;
    const int lane = t & 63;
    const int quad = lane >> 4;
    const int l16  = lane & 15;

    const int qbase = blockIdx.x * QT;
    const int strip = blockIdx.y;
    const int SS    = (N + NSTRIPS - 1) / NSTRIPS;
    const int n0    = strip * SS;
    const int nend  = (n0 + SS < N) ? (n0 + SS) : N;
    const int limit = nend - n0;                    // valid strip-local rows
    const int ntiles = (limit + NT - 1) / NT;

    // Four A-sets per wave: q rows  qbase + s*64 + wave*16 + l16,  full K=256.
    short8 afrag[4][8];
#pragma unroll
    for (int s = 0; s < 4; s++) {
        int qrow = qbase + s * 64 + wave * 16 + l16;
        const unsigned short* qp = q_bf16 + (size_t)qrow * DIM + quad * 8;
#pragma unroll
        for (int ks = 0; ks < 8; ks++)
            afrag[s][ks] = *(const short8*)(qp + ks * 32);
    }

    // per-thread top-8 keys (ascending); thread t owns query qbase+t, all columns
    uint32_t ts[STRIP_TOP];
#pragma unroll
    for (int j = 0; j < STRIP_TOP; j++) ts[j] = 0;

    const int l5  = lane >> 5;   // 0/1
    const int s32 = lane & 31;

    auto stage = [&](int tileIdx) {
        int base = n0 + tileIdx * NT;
        if (PRE) {
#pragma unroll
            for (int is = 0; is < 8; is++) {
                int rl = is * 8 + wave * 2 + l5;
                int n = base + rl; if (n >= nend) n = nend - 1;
                int chunk = s32 ^ (rl & 7);
                const unsigned short* gp = mem_bf16 + (size_t)n * DIM + chunk * 8;
                unsigned short* lp = lds_m + (is * 8 + wave * 2) * DIM;  // wave-uniform
                __builtin_amdgcn_global_load_lds((gbl_u32*)(const void*)gp,
                                                 (lds_u32*)(void*)lp, 16, 0, 0);
            }
        } else {
#pragma unroll 4
            for (int i = 0; i < 16; i++) {
                int rl = i * 4 + wave;
                int n = base + rl;
                ushort4 o;
                if (n < nend) {
                    float rinv = rnorm_mem[n];
                    float4 v = ((const float4*)(mem + (size_t)n * DIM))[lane];
                    o.x = f2bf(v.x * rinv); o.y = f2bf(v.y * rinv);
                    o.z = f2bf(v.z * rinv); o.w = f2bf(v.w * rinv);
                } else { o.x = 0; o.y = 0; o.z = 0; o.w = 0; }
                int slot = (lane >> 1) ^ (rl & 7);
                *(ushort4*)(lds_m + rl * DIM + slot * 8 + (lane & 1) * 4) = o;
            }
        }
    };

    stage(0);
    __syncthreads();

    const floatx4 one4 = {1.f, 1.f, 1.f, 1.f};   // bias: D = q·m + 1 >= 0 -> raw bits monotone
    for (int tile = 0; tile < ntiles; tile++) {
        floatx4 acc[4][4];
#pragma unroll
        for (int s = 0; s < 4; s++)
#pragma unroll
            for (int nt = 0; nt < 4; nt++) acc[s][nt] = one4;

#pragma unroll
        for (int ks = 0; ks < 8; ks++) {
#pragma unroll
            for (int nt = 0; nt < 4; nt++) {
                int row = nt * 16 + l16;
                int slot = (ks * 4 + quad) ^ (l16 & 7);
                short8 b = *(const short8*)(lds_m + row * DIM + slot * 8);
#pragma unroll
                for (int s = 0; s < 4; s++)
                    acc[s][nt] = __builtin_amdgcn_mfma_f32_16x16x32_bf16(afrag[s][ks], b, acc[s][nt], 0, 0, 0);
            }
        }
        // C layout: col(lane&15)=n, row(quad*4+r)=q.
        // Biased scores >= 0: top-16 raw bits are the monotone key halves.
#pragma unroll
        for (int s = 0; s < 4; s++) {
            int qrow = s * 64 + wave * 16 + quad * 4;
#pragma unroll
            for (int r = 0; r < 4; r++) {
                uint32_t u0 = __float_as_uint(fmaxf(acc[s][0][r], 0.f));
                uint32_t u1 = __float_as_uint(fmaxf(acc[s][1][r], 0.f));
                uint32_t u2 = __float_as_uint(fmaxf(acc[s][2][r], 0.f));
                uint32_t u3 = __float_as_uint(fmaxf(acc[s][3][r], 0.f));
                lds_s[(qrow + r) * SLOTS + l16]      = (u2 & 0xFFFF0000u) | (u0 >> 16);  // cols l16, l16+32
                lds_s[(qrow + r) * SLOTS + 16 + l16] = (u3 & 0xFFFF0000u) | (u1 >> 16);  // cols 16+l16, 48+l16
            }
        }
        __syncthreads();                     // scores visible; lds_m reads retired

        if (tile + 1 < ntiles) stage(tile + 1);  // overlaps with selection below

        // selection: thread t = query, 64 cols via 32 packed u32; key = score16<<16 | loc
        const int tloc = tile * NT;
        const uint4* sp = (const uint4*)(lds_s + t * SLOTS);
        bool full = (tloc + NT <= limit);
#pragma unroll
        for (int j4 = 0; j4 < 8; j4++) {
            uint4 v4 = sp[j4];
#pragma unroll
            for (int e = 0; e < 4; e++) {
                uint32_t v = (e == 0) ? v4.x : (e == 1) ? v4.y : (e == 2) ? v4.z : v4.w;
                int j = j4 * 4 + e;
                uint32_t key_lo = (v << 16) | (uint32_t)(tloc + j);
                uint32_t key_hi = (v & 0xFFFF0000u) | (uint32_t)(tloc + j + 32);
                if (!full) {
                    if (tloc + j >= limit)      key_lo = 0;
                    if (tloc + j + 32 >= limit) key_hi = 0;
                }
                uint32_t kmax = umaxu(key_lo, key_hi);
                uint32_t kmin = uminu(key_lo, key_hi);
                if (__any(kmax > ts[0])) {       // wave-gated: s_cbranch skips ripple
                    top8_insert(ts, kmax);        // no-op for non-qualifying lanes
                    if (__any(kmin > ts[0]))
                        top8_insert(ts, kmin);
                }
            }
        }
        __syncthreads();                     // selection + staging drained
    }

    // write candidates, converting to (score15 << 17 | gidx17) — proven key format
    size_t off = ((size_t)(qbase + t) * NSTRIPS + strip) * STRIP_TOP;
#pragma unroll
    for (int j = 0; j < STRIP_TOP; j++) {
        uint32_t k = ts[j];
        uint32_t loc = k & 0xFFFFu;
        uint32_t key2 = ((k >> 17) << 17) | (uint32_t)(n0 + (int)loc);
        cand_key[off + j] = key2;
    }
}

// ---------------- Kernel 3: key sort, top-64 cut, fp64 rescore, top-8, gather ----------------
__global__ __launch_bounds__(256) void rescore_kernel(
    const float* __restrict__ query,
    const float* __restrict__ mem,
    const uint32_t* __restrict__ cand_key,
    float* __restrict__ out,
    int B, int N)
{
    __shared__ uint32_t cs[CAND];
    __shared__ float  lds_q[DIM];
    __shared__ double red[4];
    __shared__ double qss_sh;
    __shared__ int    sel_i[RESCORE];
    __shared__ double rs[RESCORE];
    __shared__ double best_s[TOPK];
    __shared__ int    best_i[TOPK];

    const int t    = threadIdx.x;
    const int q    = blockIdx.x;
    const int lane = t & 63;
    const int wave = t >> 6;

    for (int i = t; i < CAND; i += 256)
        cs[i] = cand_key[(size_t)q * CAND + i];

    float qv = query[(size_t)q * DIM + t];
    lds_q[t] = qv;
    double p = (double)qv * (double)qv;
#pragma unroll
    for (int m = 32; m >= 1; m >>= 1) p += __shfl_xor(p, m, 64);
    if (lane == 0) red[wave] = p;
    __syncthreads();
    if (t == 0) qss_sh = red[0] + red[1] + red[2] + red[3];

    // per-wave bitonic sort (descending) of its 128-key quarter; wave-synchronous
    {
        uint32_t* qcs = cs + wave * 128;
        for (int k = 2; k <= 128; k <<= 1) {
            for (int j = k >> 1; j > 0; j >>= 1) {
                int i  = 2 * lane - (lane & (j - 1));
                int ip = i + j;
                bool up = ((i & k) == 0);
                uint32_t a = qcs[i], b2 = qcs[ip];
                bool aFirst = a > b2;
                bool doSwap = up ? (!aFirst) : aFirst;
                if (doSwap) { qcs[i] = b2; qcs[ip] = a; }
            }
        }
        if (lane < 16) sel_i[wave * 16 + lane] = (int)(qcs[lane] & IDXMASK);
    }
    __syncthreads();

    // fp64 exact cosine for the 64 selected; each wave handles its 16
    double qss = qss_sh;
    for (int r = 0; r < 16; r++) {
        int c = wave * 16 + r;
        int idx = sel_i[c];
        float4 mv = ((const float4*)(mem + (size_t)idx * DIM))[lane];
        float4 qv4 = ((const float4*)lds_q)[lane];
        double dqm = (double)mv.x * (double)qv4.x + (double)mv.y * (double)qv4.y
                   + (double)mv.z * (double)qv4.z + (double)mv.w * (double)qv4.w;
        double dmm = (double)mv.x * (double)mv.x + (double)mv.y * (double)mv.y
                   + (double)mv.z * (double)mv.z + (double)mv.w * (double)mv.w;
#pragma unroll
        for (int m = 32; m >= 1; m >>= 1) {
            dqm += __shfl_xor(dqm, m, 64);
            dmm += __shfl_xor(dmm, m, 64);
        }
        if (lane == 0)
            rs[c] = dqm / (fmax(sqrt(qss), 1e-12) * fmax(sqrt(dmm), 1e-12));
    }
    __syncthreads();

    if (t == 0) {   // serial exact top-8, tie-break (score desc, idx asc)
        double bs[TOPK]; int bi[TOPK];
        for (int i = 0; i < TOPK; i++) { bs[i] = -1e300; bi[i] = 0x7fffffff; }
        for (int c = 0; c < RESCORE; c++) {
            double s = rs[c]; int id = sel_i[c];
            bool better = (s > bs[TOPK - 1]) || (s == bs[TOPK - 1] && id < bi[TOPK - 1]);
            if (better) {
                int pos = TOPK - 1;
                while (pos > 0) {
                    bool b2 = (s > bs[pos - 1]) || (s == bs[pos - 1] && id < bi[pos - 1]);
                    if (!b2) break;
                    bs[pos] = bs[pos - 1]; bi[pos] = bi[pos - 1]; pos--;
                }
                bs[pos] = s; bi[pos] = id;
            }
        }
        for (int i = 0; i < TOPK; i++) { best_s[i] = bs[i]; best_i[i] = bi[i]; }
    }
    __syncthreads();

    size_t score_base = (size_t)B * TOPK * DIM;
    if (t < TOPK) out[score_base + (size_t)q * TOPK + t] = (float)best_s[t];

#pragma unroll
    for (int rep = 0; rep < 2; rep++) {
        int j  = t >> 5;
        int d4 = (t & 31) + rep * 32;
        int idx = best_i[j];
        float4 v = ((const float4*)(mem + (size_t)idx * DIM))[d4];
        ((float4*)(out + ((size_t)q * TOPK + j) * DIM))[d4] = v;
    }
}

extern "C" void kernel_launch(void* const* d_in, const int* in_sizes, int n_in,
                              void* d_out, int out_size, void* d_ws, size_t ws_size,
                              hipStream_t stream)
{
    const float* query = (const float*)d_in[0];
    const float* mem   = (const float*)d_in[1];
    int B = in_sizes[0] / DIM;
    int N = in_sizes[1] / DIM;

    auto align256 = [](size_t x) { return (x + 255) & ~(size_t)255; };
    size_t off = 0;
    auto alloc = [&](size_t bytes) { void* p = (char*)d_ws + off; off += align256(bytes); return p; };

    float* rnorm_mem       = (float*)alloc((size_t)N * 4);
    unsigned short* q_bf16 = (unsigned short*)alloc((size_t)B * DIM * 2);
    uint32_t* cand_key     = (uint32_t*)alloc((size_t)B * CAND * 4);
    size_t base_need = off;
    unsigned short* mem_bf16 = (unsigned short*)((char*)d_ws + base_need);
    bool pre = (base_need + align256((size_t)N * DIM * 2)) <= ws_size;
    if (!pre) mem_bf16 = nullptr;

    int prep_blocks = (N + B + 3) / 4;
    prep_kernel<<<prep_blocks, 256, 0, stream>>>(query, mem, rnorm_mem, q_bf16,
                                                 mem_bf16, B, N);

    dim3 g2((B + QT - 1) / QT, NSTRIPS);
    if (pre)
        score_select_kernel<true><<<g2, 256, 0, stream>>>(mem, rnorm_mem, mem_bf16, q_bf16,
                                                          cand_key, B, N);
    else
        score_select_kernel<false><<<g2, 256, 0, stream>>>(mem, rnorm_mem, mem_bf16, q_bf16,
                                                           cand_key, B, N);

    rescore_kernel<<<B, 256, 0, stream>>>(query, mem, cand_key, (float*)d_out, B, N);
}